// Round 17
// baseline (80.799 us; speedup 1.0000x reference)
//
#include <hip/hip_runtime.h>
#include <math.h>

#define N_NODES   150000
#define N_EDGES   1500000
#define N_GRAPHS  150
#define HID       100
#define BATCH     30
#define SEQ       5
#define NODES_PER_GRAPH 1000

#define NPB   512                            // nodes per bucket
#define NB    293                            // buckets = ceil(150000/512)
#define SBLK  128                            // sort blocks
#define SORT_T 1024                          // threads in sort kernels (was 512)
#define ACC_T 1024                           // threads in acc kernels (was 512)
#define NREP  4                              // LDS accumulator replicas
#define EPB   11720                          // edges per sort block (mult of 4; 128*11720 >= E)
#define CAP   5632                           // bucket capacity (mean 5120, +7 sigma)
#define DLMASK 511

// ---------------- S1: per-block histogram (plain stores) -------------------
__global__ __launch_bounds__(SORT_T) void k_s1(const int* __restrict__ dst,
                                               int* __restrict__ blockBase) {
    __shared__ int hist[NB];
    int t = threadIdx.x;
    for (int i = t; i < NB; i += SORT_T) hist[i] = 0;
    __syncthreads();
    int base = blockIdx.x * EPB;
    int end  = min(base + EPB, N_EDGES);
    for (int i = base + t * 4; i < end; i += SORT_T * 4) {
        int4 d = *reinterpret_cast<const int4*>(dst + i);
        atomicAdd(&hist[d.x >> 9], 1);
        atomicAdd(&hist[d.y >> 9], 1);
        atomicAdd(&hist[d.z >> 9], 1);
        atomicAdd(&hist[d.w >> 9], 1);
    }
    __syncthreads();
    for (int j = t; j < NB; j += SORT_T)
        blockBase[blockIdx.x * NB + j] = hist[j];
}

// ---------------- colscan: per-bucket exclusive scan over 128 blocks -------
__global__ __launch_bounds__(SBLK) void k_colscan(int* __restrict__ blockBase,
                                                  int* __restrict__ bucketCount) {
    __shared__ int v[SBLK];
    int j = blockIdx.x;
    int t = threadIdx.x;
    int val = blockBase[t * NB + j];
    v[t] = val;
    __syncthreads();
    for (int off = 1; off < SBLK; off <<= 1) {
        int w = (t >= off) ? v[t - off] : 0;
        __syncthreads();
        v[t] += w;
        __syncthreads();
    }
    blockBase[t * NB + j] = v[t] - val;      // exclusive prefix for block t
    if (t == SBLK - 1) bucketCount[j] = v[t];
}

// ---------------- S2: scatter packed (src<<9 | dlocal) ---------------------
__global__ __launch_bounds__(SORT_T) void k_s2(const int* __restrict__ src,
                                               const int* __restrict__ dst,
                                               const int* __restrict__ blockBase,
                                               unsigned int* __restrict__ sorted) {
    __shared__ int cursor[NB];
    __shared__ int baseS[NB];
    int t = threadIdx.x;
    const int* bb = blockBase + blockIdx.x * NB;
    for (int i = t; i < NB; i += SORT_T) {
        cursor[i] = 0;
        baseS[i] = i * CAP + bb[i];
    }
    __syncthreads();
    int base = blockIdx.x * EPB;
    int end  = min(base + EPB, N_EDGES);
    for (int i = base + t * 4; i < end; i += SORT_T * 4) {
        int4 s4 = *reinterpret_cast<const int4*>(src + i);
        int4 d4 = *reinterpret_cast<const int4*>(dst + i);
        int bk[4] = { d4.x >> 9, d4.y >> 9, d4.z >> 9, d4.w >> 9 };
        int sv[4] = { s4.x, s4.y, s4.z, s4.w };
        int dl[4] = { d4.x & DLMASK, d4.y & DLMASK, d4.z & DLMASK, d4.w & DLMASK };
        #pragma unroll
        for (int k = 0; k < 4; ++k) {
            int b = bk[k];
            int idx = atomicAdd(&cursor[b], 1);
            sorted[baseS[b] + idx] = ((unsigned int)sv[k] << 9) | (unsigned int)dl[k];
        }
    }
}

// float2 block reduction over ACC_T threads; thread supplies (bin0,bin1)
__device__ __forceinline__ void bin2_reduce_store(float2 acc, float2* red2, int t,
                                                  float2* __restrict__ outp) {
    red2[t] = acc;
    __syncthreads();
    for (int s = ACC_T / 2; s > 0; s >>= 1) {
        if (t < s) { red2[t].x += red2[t + s].x; red2[t].y += red2[t + s].y; }
        __syncthreads();
    }
    if (t == 0) *outp = red2[0];
}

// ---------------- accA: degree -> pd, px; pW[b] = bin2(dv^2) ---------------
__global__ __launch_bounds__(ACC_T) void k_accA(const unsigned int* __restrict__ sorted,
                                                const int* __restrict__ bucketCount,
                                                const float* __restrict__ x,
                                                float* __restrict__ pd,
                                                float* __restrict__ px,
                                                float2* __restrict__ pW) {
    __shared__ int degI[NREP][NPB];
    __shared__ float2 red2[ACC_T];
    int b = blockIdx.x;
    int t = threadIdx.x;
    int n0 = b << 9;
    int nn = min(NPB, N_NODES - n0);
    for (int i = t; i < NREP * NPB; i += ACC_T) ((int*)degI)[i] = 0;
    __syncthreads();
    int e0 = b * CAP, e1 = e0 + bucketCount[b];
    int rep = t & (NREP - 1);
    int nvec = (e1 - e0) >> 2;
    for (int v = t; v < nvec; v += ACC_T) {
        uint4 u4 = *reinterpret_cast<const uint4*>(sorted + e0 + v * 4);
        atomicAdd(&degI[rep][u4.x & DLMASK], 1);
        atomicAdd(&degI[rep][u4.y & DLMASK], 1);
        atomicAdd(&degI[rep][u4.z & DLMASK], 1);
        atomicAdd(&degI[rep][u4.w & DLMASK], 1);
    }
    int tail0 = e0 + (nvec << 2);
    if (tail0 + t < e1) atomicAdd(&degI[rep][sorted[tail0 + t] & DLMASK], 1);
    __syncthreads();
    int g0 = n0 / 1000;
    int thresh = (g0 + 1) * 1000 - n0;
    float2 acc = make_float2(0.f, 0.f);
    if (t < nn) {
        int dsum = 1 + degI[0][t] + degI[1][t] + degI[2][t] + degI[3][t];
        float dv = 1.0f / sqrtf((float)dsum);
        pd[n0 + t] = dv;
        px[n0 + t] = dv * x[n0 + t];
        float v = dv * dv;
        if (t < thresh) acc.x += v; else acc.y += v;
    }
    bin2_reduce_store(acc, red2, t, &pW[b]);
}

// ---------------- accB: t1 -> pa2=(dinv,a1s); pA[b] = bin2(dv^2*agg1) ------
__global__ __launch_bounds__(ACC_T) void k_accB(const unsigned int* __restrict__ sorted,
                                                const int* __restrict__ bucketCount,
                                                const float* __restrict__ pd,
                                                const float* __restrict__ px,
                                                float2* __restrict__ pa2,
                                                float2* __restrict__ pA) {
    __shared__ float t1s[NREP][NPB];
    __shared__ float2 red2[ACC_T];
    int b = blockIdx.x;
    int t = threadIdx.x;
    int n0 = b << 9;
    int nn = min(NPB, N_NODES - n0);
    for (int i = t; i < NREP * NPB; i += ACC_T) ((float*)t1s)[i] = 0.0f;
    __syncthreads();
    int e0 = b * CAP, e1 = e0 + bucketCount[b];
    int rep = t & (NREP - 1);
    int nvec = (e1 - e0) >> 2;
    for (int v = t; v < nvec; v += ACC_T) {
        uint4 u4 = *reinterpret_cast<const uint4*>(sorted + e0 + v * 4);
        float p0 = px[u4.x >> 9];
        float p1 = px[u4.y >> 9];
        float p2 = px[u4.z >> 9];
        float p3 = px[u4.w >> 9];
        atomicAdd(&t1s[rep][u4.x & DLMASK], p0);
        atomicAdd(&t1s[rep][u4.y & DLMASK], p1);
        atomicAdd(&t1s[rep][u4.z & DLMASK], p2);
        atomicAdd(&t1s[rep][u4.w & DLMASK], p3);
    }
    int tail0 = e0 + (nvec << 2);
    if (tail0 + t < e1) {
        unsigned int u = sorted[tail0 + t];
        atomicAdd(&t1s[rep][u & DLMASK], px[u >> 9]);
    }
    __syncthreads();
    int g0 = n0 / 1000;
    int thresh = (g0 + 1) * 1000 - n0;
    float2 acc = make_float2(0.f, 0.f);
    if (t < nn) {
        float dv = pd[n0 + t];
        float T1 = t1s[0][t] + t1s[1][t] + t1s[2][t] + t1s[3][t];
        float agg1 = dv * T1 + dv * px[n0 + t];   // dinv*(t1 + dinv*x)
        float a1 = dv * agg1;
        pa2[n0 + t] = make_float2(dv, a1);
        float v = dv * a1;                         // self term dv^2*agg1
        if (t < thresh) acc.x += v; else acc.y += v;
    }
    bin2_reduce_store(acc, red2, t, &pA[b]);
}

// ---------------- accG: edge terms -> pG[b]=(sa0,sa1,sw0,sw1) --------------
__global__ __launch_bounds__(ACC_T) void k_accG(const unsigned int* __restrict__ sorted,
                                                const int* __restrict__ bucketCount,
                                                const float2* __restrict__ pa2,
                                                float4* __restrict__ pG) {
    __shared__ float dvl[NPB];
    __shared__ float4 red4[ACC_T];
    int b = blockIdx.x;
    int t = threadIdx.x;
    int n0 = b << 9;
    int nn = min(NPB, N_NODES - n0);
    if (t < NPB) dvl[t] = (t < nn) ? pa2[n0 + t].x : 0.0f;
    __syncthreads();
    int g0 = n0 / 1000;
    int thresh = (g0 + 1) * 1000 - n0;
    float sa0 = 0.f, sa1 = 0.f, sw0 = 0.f, sw1 = 0.f;
    int e0 = b * CAP, e1 = e0 + bucketCount[b];
    auto proc = [&](unsigned int u) {
        int dl = (int)(u & DLMASK);
        float dvd = dvl[dl];
        float2 v = pa2[u >> 9];
        if (dl < thresh) { sw0 += dvd * v.x; sa0 += dvd * v.y; }
        else             { sw1 += dvd * v.x; sa1 += dvd * v.y; }
    };
    int nvec = (e1 - e0) >> 2;
    for (int v = t; v < nvec; v += ACC_T) {
        uint4 u4 = *reinterpret_cast<const uint4*>(sorted + e0 + v * 4);
        proc(u4.x); proc(u4.y); proc(u4.z); proc(u4.w);
    }
    int tail0 = e0 + (nvec << 2);
    if (tail0 + t < e1) proc(sorted[tail0 + t]);
    red4[t] = make_float4(sa0, sa1, sw0, sw1);
    __syncthreads();
    for (int s = ACC_T / 2; s > 0; s >>= 1) {
        if (t < s) {
            red4[t].x += red4[t + s].x; red4[t].y += red4[t + s].y;
            red4[t].z += red4[t + s].z; red4[t].w += red4[t + s].w;
        }
        __syncthreads();
    }
    if (t == 0) pG[b] = red4[0];
}

// ---------------- tail: reduce partials -> xs -> gates -> LSTM -> head -----
__global__ __launch_bounds__(512) void k_tail(const float2* __restrict__ pW,
                                              const float2* __restrict__ pA,
                                              const float4* __restrict__ pG,
                                              const float* __restrict__ W1,
                                              const float* __restrict__ b1,
                                              const float* __restrict__ W2,
                                              const float* __restrict__ b2,
                                              const float* __restrict__ W_ih,
                                              const float* __restrict__ W_hh,
                                              const float* __restrict__ b_ih,
                                              const float* __restrict__ b_hh,
                                              const float* __restrict__ W_out,
                                              const float* __restrict__ b_out,
                                              float* __restrict__ outp) {
    int b = blockIdx.x;            // 0..29
    int t = threadIdx.x;
    __shared__ float gA[N_GRAPHS], gW[N_GRAPHS];
    __shared__ float v1[HID], v2[HID];
    __shared__ float xs_l[SEQ][HID];
    __shared__ float Xg_l[SEQ][4 * HID];
    __shared__ float hs[HID], cs[HID], gsb[4 * HID];
    __shared__ float red[512];

    if (t < N_GRAPHS) { gA[t] = 0.0f; gW[t] = 0.0f; }
    __syncthreads();
    for (int j = t; j < NB; j += 512) {
        int n0 = j << 9;
        int g0 = n0 / 1000;
        float2 w2v = pW[j];
        float2 a2v = pA[j];
        float4 g4 = pG[j];
        atomicAdd(&gA[g0], a2v.x + g4.x);
        atomicAdd(&gW[g0], w2v.x + g4.z);
        if (g0 + 1 < N_GRAPHS) {
            atomicAdd(&gA[g0 + 1], a2v.y + g4.y);
            atomicAdd(&gW[g0 + 1], w2v.y + g4.w);
        }
    }
    if (t < HID) {
        float a = 0.0f, c = 0.0f;
        for (int k = 0; k < HID; ++k) {
            float w2 = W2[k * HID + t];
            a += W1[k] * w2;
            c += b1[k] * w2;
        }
        v1[t] = a; v2[t] = c;
    }
    __syncthreads();

    if (t < SEQ * HID) {
        int s = t / HID, j = t - s * HID;
        int g = b * SEQ + s;
        float ma = gA[g] * (1.0f / NODES_PER_GRAPH);
        float mw = gW[g] * (1.0f / NODES_PER_GRAPH);
        xs_l[s][j] = ma * v1[j] + mw * v2[j] + b2[j];
    }
    __syncthreads();

    float wreg[HID];
    if (t < 4 * HID) {
        const float4* wp = reinterpret_cast<const float4*>(W_ih + t * HID);
        #pragma unroll
        for (int q = 0; q < HID / 4; ++q) {
            float4 w4 = wp[q];
            wreg[4*q+0] = w4.x; wreg[4*q+1] = w4.y; wreg[4*q+2] = w4.z; wreg[4*q+3] = w4.w;
        }
        float bias = b_ih[t] + b_hh[t];
        for (int s = 0; s < SEQ; ++s) {
            float acc = bias;
            #pragma unroll
            for (int k = 0; k < HID; ++k)
                acc += xs_l[s][k] * wreg[k];
            Xg_l[s][t] = acc;
        }
        wp = reinterpret_cast<const float4*>(W_hh + t * HID);
        #pragma unroll
        for (int q = 0; q < HID / 4; ++q) {
            float4 w4 = wp[q];
            wreg[4*q+0] = w4.x; wreg[4*q+1] = w4.y; wreg[4*q+2] = w4.z; wreg[4*q+3] = w4.w;
        }
    }
    if (t < HID) { hs[t] = 0.0f; cs[t] = 0.0f; }
    __syncthreads();

    for (int step = 0; step < SEQ; ++step) {
        if (t < 4 * HID) {
            float acc = Xg_l[step][t];
            #pragma unroll
            for (int k = 0; k < HID; ++k)
                acc += hs[k] * wreg[k];
            gsb[t] = acc;
        }
        __syncthreads();
        if (t < HID) {
            float ig = 1.0f / (1.0f + expf(-gsb[t]));
            float fg = 1.0f / (1.0f + expf(-gsb[HID + t]));
            float gg = tanhf(gsb[2 * HID + t]);
            float og = 1.0f / (1.0f + expf(-gsb[3 * HID + t]));
            float c  = fg * cs[t] + ig * gg;
            cs[t] = c;
            hs[t] = og * tanhf(c);
        }
        __syncthreads();
    }

    float v = (t < HID) ? hs[t] * W_out[t] : 0.0f;
    red[t] = v;
    __syncthreads();
    for (int s = 256; s > 0; s >>= 1) {
        if (t < s) red[t] += red[t + s];
        __syncthreads();
    }
    if (t == 0) outp[b] = red[0] + b_out[0];
}

// ---------------- launch ----------------
static inline char* align_up(char* p, size_t a) {
    return (char*)(((uintptr_t)p + (a - 1)) & ~(uintptr_t)(a - 1));
}

extern "C" void kernel_launch(void* const* d_in, const int* in_sizes, int n_in,
                              void* d_out, int out_size, void* d_ws, size_t ws_size,
                              hipStream_t stream) {
    const float* x    = (const float*)d_in[0];
    const int*   ei   = (const int*)d_in[1];
    const int*   srcp = ei;
    const int*   dstp = ei + N_EDGES;
    const float* W1   = (const float*)d_in[3];
    const float* b1   = (const float*)d_in[4];
    const float* W2   = (const float*)d_in[5];
    const float* b2   = (const float*)d_in[6];
    const float* W_ih = (const float*)d_in[7];
    const float* W_hh = (const float*)d_in[8];
    const float* b_ih = (const float*)d_in[9];
    const float* b_hh = (const float*)d_in[10];
    const float* W_out= (const float*)d_in[11];
    const float* b_out= (const float*)d_in[12];
    float* out = (float*)d_out;

    // workspace layout (64B-aligned regions; uint4 paths need 16B)
    char* w = (char*)d_ws;
    int*  bucketCount = (int*)w;             w = align_up(w + NB * sizeof(int), 64);
    int*  blockBase   = (int*)w;             w = align_up(w + (size_t)SBLK * NB * sizeof(int), 64);
    unsigned int* sorted = (unsigned int*)w; w = align_up(w + (size_t)NB * CAP * sizeof(unsigned int), 64);
    float*  pd  = (float*)w;                 w = align_up(w + (size_t)N_NODES * sizeof(float), 64);
    float*  px  = (float*)w;                 w = align_up(w + (size_t)N_NODES * sizeof(float), 64);
    float2* pa2 = (float2*)w;                w = align_up(w + (size_t)N_NODES * sizeof(float2), 64);
    float2* pW  = (float2*)w;                w = align_up(w + NB * sizeof(float2), 64);
    float2* pA  = (float2*)w;                w = align_up(w + NB * sizeof(float2), 64);
    float4* pG  = (float4*)w;                w = align_up(w + NB * sizeof(float4), 64);

    k_s1     <<<SBLK, SORT_T, 0, stream>>>(dstp, blockBase);
    k_colscan<<<NB, SBLK, 0, stream>>>(blockBase, bucketCount);
    k_s2     <<<SBLK, SORT_T, 0, stream>>>(srcp, dstp, blockBase, sorted);
    k_accA   <<<NB, ACC_T, 0, stream>>>(sorted, bucketCount, x, pd, px, pW);
    k_accB   <<<NB, ACC_T, 0, stream>>>(sorted, bucketCount, pd, px, pa2, pA);
    k_accG   <<<NB, ACC_T, 0, stream>>>(sorted, bucketCount, pa2, pG);
    k_tail   <<<BATCH, 512, 0, stream>>>(pW, pA, pG, W1, b1, W2, b2,
                                         W_ih, W_hh, b_ih, b_hh, W_out, b_out, out);
}

// Round 18
// 79.087 us; speedup vs baseline: 1.0216x; 1.0216x over previous
//
#include <hip/hip_runtime.h>
#include <math.h>

#define N_NODES   150000
#define N_EDGES   1500000
#define N_GRAPHS  150
#define HID       100
#define BATCH     30
#define SEQ       5
#define NODES_PER_GRAPH 1000

#define NPB   512                            // nodes per bucket
#define NB    293                            // buckets = ceil(150000/512)
#define SBLK  256                            // sort blocks (full CU coverage)
#define SORT_T 1024                          // threads in sort kernels
#define ACC_T 1024                           // threads in acc kernels
#define NREP  4                              // LDS accumulator replicas (acc)
#define EPB   5860                           // edges per sort block (mult of 4; 256*5860 >= E)
#define CAP   5632                           // bucket capacity (mean 5120, +7 sigma)
#define DLMASK 511

// ---------------- S1: per-block histogram (2 replicas, plain stores) -------
__global__ __launch_bounds__(SORT_T) void k_s1(const int* __restrict__ dst,
                                               int* __restrict__ blockBase) {
    __shared__ int hist[2][NB];
    int t = threadIdx.x;
    for (int i = t; i < 2 * NB; i += SORT_T) ((int*)hist)[i] = 0;
    __syncthreads();
    int rep = t & 1;
    int base = blockIdx.x * EPB;
    int end  = min(base + EPB, N_EDGES);
    for (int i = base + t * 4; i < end; i += SORT_T * 4) {
        int4 d = *reinterpret_cast<const int4*>(dst + i);
        atomicAdd(&hist[rep][d.x >> 9], 1);
        atomicAdd(&hist[rep][d.y >> 9], 1);
        atomicAdd(&hist[rep][d.z >> 9], 1);
        atomicAdd(&hist[rep][d.w >> 9], 1);
    }
    __syncthreads();
    for (int j = t; j < NB; j += SORT_T)
        blockBase[blockIdx.x * NB + j] = hist[0][j] + hist[1][j];
}

// ---------------- colscan: per-bucket exclusive scan over 256 blocks -------
__global__ __launch_bounds__(SBLK) void k_colscan(int* __restrict__ blockBase,
                                                  int* __restrict__ bucketCount) {
    __shared__ int v[SBLK];
    int j = blockIdx.x;
    int t = threadIdx.x;
    int val = blockBase[t * NB + j];
    v[t] = val;
    __syncthreads();
    for (int off = 1; off < SBLK; off <<= 1) {
        int w = (t >= off) ? v[t - off] : 0;
        __syncthreads();
        v[t] += w;
        __syncthreads();
    }
    blockBase[t * NB + j] = v[t] - val;      // exclusive prefix for block t
    if (t == SBLK - 1) bucketCount[j] = v[t];
}

// ---------------- S2: scatter packed (src<<9 | dlocal) ---------------------
__global__ __launch_bounds__(SORT_T) void k_s2(const int* __restrict__ src,
                                               const int* __restrict__ dst,
                                               const int* __restrict__ blockBase,
                                               unsigned int* __restrict__ sorted) {
    __shared__ int cursor[NB];
    __shared__ int baseS[NB];
    int t = threadIdx.x;
    const int* bb = blockBase + blockIdx.x * NB;
    for (int i = t; i < NB; i += SORT_T) {
        cursor[i] = 0;
        baseS[i] = i * CAP + bb[i];
    }
    __syncthreads();
    int base = blockIdx.x * EPB;
    int end  = min(base + EPB, N_EDGES);
    for (int i = base + t * 4; i < end; i += SORT_T * 4) {
        int4 s4 = *reinterpret_cast<const int4*>(src + i);
        int4 d4 = *reinterpret_cast<const int4*>(dst + i);
        int bk[4] = { d4.x >> 9, d4.y >> 9, d4.z >> 9, d4.w >> 9 };
        int sv[4] = { s4.x, s4.y, s4.z, s4.w };
        int dl[4] = { d4.x & DLMASK, d4.y & DLMASK, d4.z & DLMASK, d4.w & DLMASK };
        #pragma unroll
        for (int k = 0; k < 4; ++k) {
            int b = bk[k];
            int idx = atomicAdd(&cursor[b], 1);
            sorted[baseS[b] + idx] = ((unsigned int)sv[k] << 9) | (unsigned int)dl[k];
        }
    }
}

// float2 block reduction over ACC_T threads; thread supplies (bin0,bin1)
__device__ __forceinline__ void bin2_reduce_store(float2 acc, float2* red2, int t,
                                                  float2* __restrict__ outp) {
    red2[t] = acc;
    __syncthreads();
    for (int s = ACC_T / 2; s > 0; s >>= 1) {
        if (t < s) { red2[t].x += red2[t + s].x; red2[t].y += red2[t + s].y; }
        __syncthreads();
    }
    if (t == 0) *outp = red2[0];
}

// ---------------- accA: degree -> pd, px; pW[b] = bin2(dv^2) ---------------
__global__ __launch_bounds__(ACC_T) void k_accA(const unsigned int* __restrict__ sorted,
                                                const int* __restrict__ bucketCount,
                                                const float* __restrict__ x,
                                                float* __restrict__ pd,
                                                float* __restrict__ px,
                                                float2* __restrict__ pW) {
    __shared__ int degI[NREP][NPB];
    __shared__ float2 red2[ACC_T];
    int b = blockIdx.x;
    int t = threadIdx.x;
    int n0 = b << 9;
    int nn = min(NPB, N_NODES - n0);
    for (int i = t; i < NREP * NPB; i += ACC_T) ((int*)degI)[i] = 0;
    __syncthreads();
    int e0 = b * CAP, e1 = e0 + bucketCount[b];
    int rep = t & (NREP - 1);
    int nvec = (e1 - e0) >> 2;
    for (int v = t; v < nvec; v += ACC_T) {
        uint4 u4 = *reinterpret_cast<const uint4*>(sorted + e0 + v * 4);
        atomicAdd(&degI[rep][u4.x & DLMASK], 1);
        atomicAdd(&degI[rep][u4.y & DLMASK], 1);
        atomicAdd(&degI[rep][u4.z & DLMASK], 1);
        atomicAdd(&degI[rep][u4.w & DLMASK], 1);
    }
    int tail0 = e0 + (nvec << 2);
    if (tail0 + t < e1) atomicAdd(&degI[rep][sorted[tail0 + t] & DLMASK], 1);
    __syncthreads();
    int g0 = n0 / 1000;
    int thresh = (g0 + 1) * 1000 - n0;
    float2 acc = make_float2(0.f, 0.f);
    if (t < nn) {
        int dsum = 1 + degI[0][t] + degI[1][t] + degI[2][t] + degI[3][t];
        float dv = 1.0f / sqrtf((float)dsum);
        pd[n0 + t] = dv;
        px[n0 + t] = dv * x[n0 + t];
        float v = dv * dv;
        if (t < thresh) acc.x += v; else acc.y += v;
    }
    bin2_reduce_store(acc, red2, t, &pW[b]);
}

// ---------------- accB: t1 -> pa2=(dinv,a1s); pA[b] = bin2(dv^2*agg1) ------
__global__ __launch_bounds__(ACC_T) void k_accB(const unsigned int* __restrict__ sorted,
                                                const int* __restrict__ bucketCount,
                                                const float* __restrict__ pd,
                                                const float* __restrict__ px,
                                                float2* __restrict__ pa2,
                                                float2* __restrict__ pA) {
    __shared__ float t1s[NREP][NPB];
    __shared__ float2 red2[ACC_T];
    int b = blockIdx.x;
    int t = threadIdx.x;
    int n0 = b << 9;
    int nn = min(NPB, N_NODES - n0);
    for (int i = t; i < NREP * NPB; i += ACC_T) ((float*)t1s)[i] = 0.0f;
    __syncthreads();
    int e0 = b * CAP, e1 = e0 + bucketCount[b];
    int rep = t & (NREP - 1);
    int nvec = (e1 - e0) >> 2;
    for (int v = t; v < nvec; v += ACC_T) {
        uint4 u4 = *reinterpret_cast<const uint4*>(sorted + e0 + v * 4);
        float p0 = px[u4.x >> 9];
        float p1 = px[u4.y >> 9];
        float p2 = px[u4.z >> 9];
        float p3 = px[u4.w >> 9];
        atomicAdd(&t1s[rep][u4.x & DLMASK], p0);
        atomicAdd(&t1s[rep][u4.y & DLMASK], p1);
        atomicAdd(&t1s[rep][u4.z & DLMASK], p2);
        atomicAdd(&t1s[rep][u4.w & DLMASK], p3);
    }
    int tail0 = e0 + (nvec << 2);
    if (tail0 + t < e1) {
        unsigned int u = sorted[tail0 + t];
        atomicAdd(&t1s[rep][u & DLMASK], px[u >> 9]);
    }
    __syncthreads();
    int g0 = n0 / 1000;
    int thresh = (g0 + 1) * 1000 - n0;
    float2 acc = make_float2(0.f, 0.f);
    if (t < nn) {
        float dv = pd[n0 + t];
        float T1 = t1s[0][t] + t1s[1][t] + t1s[2][t] + t1s[3][t];
        float agg1 = dv * T1 + dv * px[n0 + t];   // dinv*(t1 + dinv*x)
        float a1 = dv * agg1;
        pa2[n0 + t] = make_float2(dv, a1);
        float v = dv * a1;                         // self term dv^2*agg1
        if (t < thresh) acc.x += v; else acc.y += v;
    }
    bin2_reduce_store(acc, red2, t, &pA[b]);
}

// ---------------- accG: edge terms -> pG[b]=(sa0,sa1,sw0,sw1) --------------
__global__ __launch_bounds__(ACC_T) void k_accG(const unsigned int* __restrict__ sorted,
                                                const int* __restrict__ bucketCount,
                                                const float2* __restrict__ pa2,
                                                float4* __restrict__ pG) {
    __shared__ float dvl[NPB];
    __shared__ float4 red4[ACC_T];
    int b = blockIdx.x;
    int t = threadIdx.x;
    int n0 = b << 9;
    int nn = min(NPB, N_NODES - n0);
    if (t < NPB) dvl[t] = (t < nn) ? pa2[n0 + t].x : 0.0f;
    __syncthreads();
    int g0 = n0 / 1000;
    int thresh = (g0 + 1) * 1000 - n0;
    float sa0 = 0.f, sa1 = 0.f, sw0 = 0.f, sw1 = 0.f;
    int e0 = b * CAP, e1 = e0 + bucketCount[b];
    auto proc = [&](unsigned int u) {
        int dl = (int)(u & DLMASK);
        float dvd = dvl[dl];
        float2 v = pa2[u >> 9];
        if (dl < thresh) { sw0 += dvd * v.x; sa0 += dvd * v.y; }
        else             { sw1 += dvd * v.x; sa1 += dvd * v.y; }
    };
    int nvec = (e1 - e0) >> 2;
    for (int v = t; v < nvec; v += ACC_T) {
        uint4 u4 = *reinterpret_cast<const uint4*>(sorted + e0 + v * 4);
        proc(u4.x); proc(u4.y); proc(u4.z); proc(u4.w);
    }
    int tail0 = e0 + (nvec << 2);
    if (tail0 + t < e1) proc(sorted[tail0 + t]);
    red4[t] = make_float4(sa0, sa1, sw0, sw1);
    __syncthreads();
    for (int s = ACC_T / 2; s > 0; s >>= 1) {
        if (t < s) {
            red4[t].x += red4[t + s].x; red4[t].y += red4[t + s].y;
            red4[t].z += red4[t + s].z; red4[t].w += red4[t + s].w;
        }
        __syncthreads();
    }
    if (t == 0) pG[b] = red4[0];
}

// ---------------- tail: reduce partials -> xs -> gates -> LSTM -> head -----
__global__ __launch_bounds__(512) void k_tail(const float2* __restrict__ pW,
                                              const float2* __restrict__ pA,
                                              const float4* __restrict__ pG,
                                              const float* __restrict__ W1,
                                              const float* __restrict__ b1,
                                              const float* __restrict__ W2,
                                              const float* __restrict__ b2,
                                              const float* __restrict__ W_ih,
                                              const float* __restrict__ W_hh,
                                              const float* __restrict__ b_ih,
                                              const float* __restrict__ b_hh,
                                              const float* __restrict__ W_out,
                                              const float* __restrict__ b_out,
                                              float* __restrict__ outp) {
    int b = blockIdx.x;            // 0..29
    int t = threadIdx.x;
    __shared__ float gA[N_GRAPHS], gW[N_GRAPHS];
    __shared__ float v1[HID], v2[HID];
    __shared__ float xs_l[SEQ][HID];
    __shared__ float Xg_l[SEQ][4 * HID];
    __shared__ float hs[HID], cs[HID], gsb[4 * HID];
    __shared__ float red[512];

    if (t < N_GRAPHS) { gA[t] = 0.0f; gW[t] = 0.0f; }
    __syncthreads();
    for (int j = t; j < NB; j += 512) {
        int n0 = j << 9;
        int g0 = n0 / 1000;
        float2 w2v = pW[j];
        float2 a2v = pA[j];
        float4 g4 = pG[j];
        atomicAdd(&gA[g0], a2v.x + g4.x);
        atomicAdd(&gW[g0], w2v.x + g4.z);
        if (g0 + 1 < N_GRAPHS) {
            atomicAdd(&gA[g0 + 1], a2v.y + g4.y);
            atomicAdd(&gW[g0 + 1], w2v.y + g4.w);
        }
    }
    if (t < HID) {
        float a = 0.0f, c = 0.0f;
        for (int k = 0; k < HID; ++k) {
            float w2 = W2[k * HID + t];
            a += W1[k] * w2;
            c += b1[k] * w2;
        }
        v1[t] = a; v2[t] = c;
    }
    __syncthreads();

    if (t < SEQ * HID) {
        int s = t / HID, j = t - s * HID;
        int g = b * SEQ + s;
        float ma = gA[g] * (1.0f / NODES_PER_GRAPH);
        float mw = gW[g] * (1.0f / NODES_PER_GRAPH);
        xs_l[s][j] = ma * v1[j] + mw * v2[j] + b2[j];
    }
    __syncthreads();

    float wreg[HID];
    if (t < 4 * HID) {
        const float4* wp = reinterpret_cast<const float4*>(W_ih + t * HID);
        #pragma unroll
        for (int q = 0; q < HID / 4; ++q) {
            float4 w4 = wp[q];
            wreg[4*q+0] = w4.x; wreg[4*q+1] = w4.y; wreg[4*q+2] = w4.z; wreg[4*q+3] = w4.w;
        }
        float bias = b_ih[t] + b_hh[t];
        for (int s = 0; s < SEQ; ++s) {
            float acc = bias;
            #pragma unroll
            for (int k = 0; k < HID; ++k)
                acc += xs_l[s][k] * wreg[k];
            Xg_l[s][t] = acc;
        }
        wp = reinterpret_cast<const float4*>(W_hh + t * HID);
        #pragma unroll
        for (int q = 0; q < HID / 4; ++q) {
            float4 w4 = wp[q];
            wreg[4*q+0] = w4.x; wreg[4*q+1] = w4.y; wreg[4*q+2] = w4.z; wreg[4*q+3] = w4.w;
        }
    }
    if (t < HID) { hs[t] = 0.0f; cs[t] = 0.0f; }
    __syncthreads();

    for (int step = 0; step < SEQ; ++step) {
        if (t < 4 * HID) {
            float acc = Xg_l[step][t];
            #pragma unroll
            for (int k = 0; k < HID; ++k)
                acc += hs[k] * wreg[k];
            gsb[t] = acc;
        }
        __syncthreads();
        if (t < HID) {
            float ig = 1.0f / (1.0f + expf(-gsb[t]));
            float fg = 1.0f / (1.0f + expf(-gsb[HID + t]));
            float gg = tanhf(gsb[2 * HID + t]);
            float og = 1.0f / (1.0f + expf(-gsb[3 * HID + t]));
            float c  = fg * cs[t] + ig * gg;
            cs[t] = c;
            hs[t] = og * tanhf(c);
        }
        __syncthreads();
    }

    float v = (t < HID) ? hs[t] * W_out[t] : 0.0f;
    red[t] = v;
    __syncthreads();
    for (int s = 256; s > 0; s >>= 1) {
        if (t < s) red[t] += red[t + s];
        __syncthreads();
    }
    if (t == 0) outp[b] = red[0] + b_out[0];
}

// ---------------- launch ----------------
static inline char* align_up(char* p, size_t a) {
    return (char*)(((uintptr_t)p + (a - 1)) & ~(uintptr_t)(a - 1));
}

extern "C" void kernel_launch(void* const* d_in, const int* in_sizes, int n_in,
                              void* d_out, int out_size, void* d_ws, size_t ws_size,
                              hipStream_t stream) {
    const float* x    = (const float*)d_in[0];
    const int*   ei   = (const int*)d_in[1];
    const int*   srcp = ei;
    const int*   dstp = ei + N_EDGES;
    const float* W1   = (const float*)d_in[3];
    const float* b1   = (const float*)d_in[4];
    const float* W2   = (const float*)d_in[5];
    const float* b2   = (const float*)d_in[6];
    const float* W_ih = (const float*)d_in[7];
    const float* W_hh = (const float*)d_in[8];
    const float* b_ih = (const float*)d_in[9];
    const float* b_hh = (const float*)d_in[10];
    const float* W_out= (const float*)d_in[11];
    const float* b_out= (const float*)d_in[12];
    float* out = (float*)d_out;

    // workspace layout (64B-aligned regions; uint4 paths need 16B)
    char* w = (char*)d_ws;
    int*  bucketCount = (int*)w;             w = align_up(w + NB * sizeof(int), 64);
    int*  blockBase   = (int*)w;             w = align_up(w + (size_t)SBLK * NB * sizeof(int), 64);
    unsigned int* sorted = (unsigned int*)w; w = align_up(w + (size_t)NB * CAP * sizeof(unsigned int), 64);
    float*  pd  = (float*)w;                 w = align_up(w + (size_t)N_NODES * sizeof(float), 64);
    float*  px  = (float*)w;                 w = align_up(w + (size_t)N_NODES * sizeof(float), 64);
    float2* pa2 = (float2*)w;                w = align_up(w + (size_t)N_NODES * sizeof(float2), 64);
    float2* pW  = (float2*)w;                w = align_up(w + NB * sizeof(float2), 64);
    float2* pA  = (float2*)w;                w = align_up(w + NB * sizeof(float2), 64);
    float4* pG  = (float4*)w;                w = align_up(w + NB * sizeof(float4), 64);

    k_s1     <<<SBLK, SORT_T, 0, stream>>>(dstp, blockBase);
    k_colscan<<<NB, SBLK, 0, stream>>>(blockBase, bucketCount);
    k_s2     <<<SBLK, SORT_T, 0, stream>>>(srcp, dstp, blockBase, sorted);
    k_accA   <<<NB, ACC_T, 0, stream>>>(sorted, bucketCount, x, pd, px, pW);
    k_accB   <<<NB, ACC_T, 0, stream>>>(sorted, bucketCount, pd, px, pa2, pA);
    k_accG   <<<NB, ACC_T, 0, stream>>>(sorted, bucketCount, pa2, pG);
    k_tail   <<<BATCH, 512, 0, stream>>>(pW, pA, pG, W1, b1, W2, b2,
                                         W_ih, W_hh, b_ih, b_hh, W_out, b_out, out);
}